// Round 3
// baseline (3586.484 us; speedup 1.0000x reference)
//
#include <hip/hip_runtime.h>
#include <cstdint>
#include <cstddef>

#define E_CNT   262144
#define NNODES  50000
#define EMB     512
#define KD      1536
#define ND      2048
#define NG      64
#define XROWS   (NNODES + E_CNT)

typedef unsigned short u16;
typedef short  s8v __attribute__((ext_vector_type(8)));
typedef float  f4v __attribute__((ext_vector_type(4)));

// ---- workspace layout (bytes) ----
#define WS_XB   0u                      // XROWS*512 bf16           = 319,635,456
#define WS_WT   319635456u              // 2048*1536 bf16           =   6,291,456
#define WS_B1   325926912u              // 2048 f32
#define WS_W2   325935104u              // 2048 f32
#define WS_P    325943296u              // 16*E f32                 =  16,777,216
#define WS_END  342720512u

__device__ __forceinline__ u16 f2bf(float f) {
    union { float f; uint32_t u; } v; v.f = f;
    uint32_t u = v.u;
    return (u16)((u + 0x7FFFu + ((u >> 16) & 1u)) >> 16);
}

// ---------------- x -> bf16 ----------------
__global__ void cvt_x(const float* __restrict__ x, uint32_t* __restrict__ xb) {
    size_t i = ((size_t)blockIdx.x * 256 + threadIdx.x) * 8;
    float4 a = *(const float4*)(x + i);
    float4 b = *(const float4*)(x + i + 4);
    uint4 r;
    r.x = (uint32_t)f2bf(a.x) | ((uint32_t)f2bf(a.y) << 16);
    r.y = (uint32_t)f2bf(a.z) | ((uint32_t)f2bf(a.w) << 16);
    r.z = (uint32_t)f2bf(b.x) | ((uint32_t)f2bf(b.y) << 16);
    r.w = (uint32_t)f2bf(b.z) | ((uint32_t)f2bf(b.w) << 16);
    *(uint4*)((char*)xb + i * 2) = r;
}

// ------- W1e|W1f -> WT[n][k] bf16 (tiled transpose) -------
__global__ void prep_w(const float* __restrict__ W1e, const float* __restrict__ W1f,
                       u16* __restrict__ wt) {
    __shared__ float tile[32][33];
    int n0 = blockIdx.x * 32, k0 = blockIdx.y * 32;
    int tx = threadIdx.x & 31, ty = threadIdx.x >> 5;   // 32 x 8
#pragma unroll
    for (int i = 0; i < 4; ++i) {
        int k = k0 + ty + i * 8, n = n0 + tx;
        float v = (n < 1024) ? W1e[k * 1024 + n] : W1f[k * 1024 + (n - 1024)];
        tile[ty + i * 8][tx] = v;
    }
    __syncthreads();
#pragma unroll
    for (int i = 0; i < 4; ++i) {
        int nl = ty + i * 8, kl = tx;
        wt[(size_t)(n0 + nl) * KD + k0 + kl] = f2bf(tile[kl][nl]);
    }
}

__global__ void prep_small(const float* __restrict__ b1e, const float* __restrict__ b1f,
                           const float* __restrict__ W2e, const float* __restrict__ W2f,
                           float* __restrict__ b1c, float* __restrict__ w2c) {
    int n = blockIdx.x * 256 + threadIdx.x;  // 0..2047
    if (n < 1024) { b1c[n] = b1e[n]; w2c[n] = W2e[n]; }
    else          { b1c[n] = b1f[n - 1024]; w2c[n] = W2f[n - 1024]; }
}

// ---------------- fused GEMM + gelu + W2-reduce ----------------
// grid = (16 n-tiles, 2048 m-tiles), 256 threads, 1 block/CU.
// 3-deep LDS pipeline with counted vmcnt (2-phase prefetch lookahead),
// XOR-swizzled tiles, XCD-grouped blocks.
__global__ __launch_bounds__(256, 1)
void gemm_mlp(const u16* __restrict__ xb, const u16* __restrict__ wt,
              const float* __restrict__ b1c, const float* __restrict__ w2c,
              const int* __restrict__ ei, float* __restrict__ P) {
    __shared__ u16 Al[3][128 * 64];   // [buf][row][64] ; row = 128B ; swizzled units
    __shared__ u16 Bl[3][128 * 64];
    __shared__ float part[128];

    // ---- XCD-grouping remap: dispatch order o = bx + 16*by ; XCD = o % 8.
    const unsigned o = blockIdx.x + (blockIdx.y << 4);
    const int mb = (int)((o & 7u) + ((o >> 7) << 3));
    const int nb = (int)((o >> 3) & 15u);
    const int m0 = mb << 7;
    const int n0 = nb << 7;
    const int t  = threadIdx.x;
    const int l  = t & 63;
    const int w  = t >> 6;

    // staging assignment: thread covers rows {rbase+32i}, 16B unit `unit`
    const int rbase = t >> 3;           // 0..31
    const int unit  = t & 7;            // 0..7
    const int sunit = (unit ^ (rbase & 7)) << 3;   // pre-swizzled source column

    int srcs[4], dsts[4];
#pragma unroll
    for (int i = 0; i < 4; ++i) {
        int e = m0 + rbase + i * 32;
        srcs[i] = ei[e];
        dsts[i] = ei[E_CNT + e];
    }

    if (t < 128) part[t] = 0.0f;

    const int wm = (w & 1) << 6;        // wave tile origin in m
    const int wn = (w >> 1) << 6;       // wave tile origin in n

    float b1v[4], w2v[4];
#pragma unroll
    for (int nf = 0; nf < 4; ++nf) {
        int n = n0 + wn + nf * 16 + (l & 15);
        b1v[nf] = b1c[n];
        w2v[nf] = w2c[n];
    }

    f4v acc[4][4];
#pragma unroll
    for (int mf = 0; mf < 4; ++mf)
#pragma unroll
        for (int nf = 0; nf < 4; ++nf)
            acc[mf][nf] = (f4v){0.f, 0.f, 0.f, 0.f};

    // ---- staging: issue 8 global_load_lds for K-tile kt into Ad/Bd ----
    auto stage = [&](u16* Ad, u16* Bd, int kt) {
        const int k0   = kt << 6;
        const int seg  = k0 >> 9;       // 0:src 1:dst 2:edge-token
        const int koff = k0 & 511;
#pragma unroll
        for (int i = 0; i < 4; ++i) {
            int row;
            if (seg == 0)      row = srcs[i];
            else if (seg == 1) row = dsts[i];
            else               row = NNODES + m0 + rbase + i * 32;
            const u16* g = xb + (size_t)row * EMB + koff + sunit;
            __builtin_amdgcn_global_load_lds(
                (const __attribute__((address_space(1))) void*)g,
                (__attribute__((address_space(3))) void*)(Ad + (i * 32 + w * 8) * 64),
                16, 0, 0);
        }
#pragma unroll
        for (int i = 0; i < 4; ++i) {
            int n = n0 + rbase + i * 32;
            const u16* g = wt + (size_t)n * KD + k0 + sunit;
            __builtin_amdgcn_global_load_lds(
                (const __attribute__((address_space(1))) void*)g,
                (__attribute__((address_space(3))) void*)(Bd + (i * 32 + w * 8) * 64),
                16, 0, 0);
        }
    };

    // read-side physical unit offsets (elements)
    const int po0 = (((l >> 4) ^ (l & 7)) << 3);
    const int po1 = (((4 | (l >> 4)) ^ (l & 7)) << 3);
    const int l15 = l & 15;

    // ---- compute one K-tile from buffers Ab/Bb: 16 ds_read_b128 then 32 MFMA ----
    auto compute = [&](const u16* Ab, const u16* Bb) {
        s8v a[2][4], b[2][4];
#pragma unroll
        for (int mf = 0; mf < 4; ++mf) {
            a[0][mf] = *(const s8v*)(Ab + (wm + mf * 16 + l15) * 64 + po0);
            a[1][mf] = *(const s8v*)(Ab + (wm + mf * 16 + l15) * 64 + po1);
        }
#pragma unroll
        for (int nf = 0; nf < 4; ++nf) {
            b[0][nf] = *(const s8v*)(Bb + (wn + nf * 16 + l15) * 64 + po0);
            b[1][nf] = *(const s8v*)(Bb + (wn + nf * 16 + l15) * 64 + po1);
        }
        __builtin_amdgcn_s_setprio(1);
#pragma unroll
        for (int ks = 0; ks < 2; ++ks)
#pragma unroll
            for (int mf = 0; mf < 4; ++mf)
#pragma unroll
                for (int nf = 0; nf < 4; ++nf)
                    acc[mf][nf] = __builtin_amdgcn_mfma_f32_16x16x32_bf16(
                        a[ks][mf], b[ks][nf], acc[mf][nf], 0, 0, 0);
        __builtin_amdgcn_s_setprio(0);
    };

    // rotating buffer pointers: cur (reading), nxt (in flight), stg (to stage)
    u16 *Ac = Al[0], *An = Al[1], *As = Al[2];
    u16 *Bc = Bl[0], *Bn = Bl[1], *Bs = Bl[2];

    // prologue: tiles 0 and 1 in flight
    stage(Ac, Bc, 0);
    stage(An, Bn, 1);
    __syncthreads();                       // drains vmcnt; buf0,buf1 ready

    stage(As, Bs, 2);                      // tile 2 in flight (vm: 8)
    compute(Ac, Bc);                       // kt = 0
    { u16* tA = Ac; Ac = An; An = As; As = tA;
      u16* tB = Bc; Bc = Bn; Bn = Bs; Bs = tB; }

    for (int kt = 1; kt <= 21; ++kt) {
        asm volatile("s_waitcnt vmcnt(8)" ::: "memory");  // stage(kt) landed
        __builtin_amdgcn_s_barrier();                     // buf(kt) ready for all; staged buf free
        stage(As, Bs, kt + 2);                            // vm: 8 -> 16
        compute(Ac, Bc);
        { u16* tA = Ac; Ac = An; An = As; As = tA;
          u16* tB = Bc; Bc = Bn; Bn = Bs; Bs = tB; }
    }
    // kt = 22: stage(23) still in flight
    asm volatile("s_waitcnt vmcnt(8)" ::: "memory");
    __builtin_amdgcn_s_barrier();
    compute(Ac, Bc);
    { u16* tA = Ac; Ac = An; An = As; As = tA;
      u16* tB = Bc; Bc = Bn; Bn = Bs; Bs = tB; }
    // kt = 23: last tile
    asm volatile("s_waitcnt vmcnt(0)" ::: "memory");
    __builtin_amdgcn_s_barrier();
    compute(Ac, Bc);

    // ---- epilogue: bias + gelu(tanh) + *W2, reduce over this block's 128 cols ----
    // C layout: m = wm + mf*16 + (l>>4)*4 + r ; n = wn + nf*16 + (l&15)
#pragma unroll
    for (int mf = 0; mf < 4; ++mf) {
#pragma unroll
        for (int r = 0; r < 4; ++r) {
            float s = 0.f;
#pragma unroll
            for (int nf = 0; nf < 4; ++nf) {
                float h  = acc[mf][nf][r] + b1v[nf];
                float x2 = h * h;
                float pp = fmaf(x2, 0.044715f, 1.0f);
                float u2 = 1.5957691216f * h * pp;        // 2*sqrt(2/pi)*(h+0.044715h^3)
                float ex = __expf(-u2);
                float sg = __builtin_amdgcn_rcpf(1.0f + ex); // gelu = h*sigmoid(u2)
                s = fmaf(h * sg, w2v[nf], s);
            }
            s += __shfl_xor(s, 1);
            s += __shfl_xor(s, 2);
            s += __shfl_xor(s, 4);
            s += __shfl_xor(s, 8);
            if ((l & 15) == 0) {
                int m = wm + mf * 16 + ((l >> 4) << 2) + r;
                atomicAdd(&part[m], s);
            }
        }
    }
    __syncthreads();
    if (t < 128) P[(size_t)nb * E_CNT + m0 + t] = part[t];
}

// ---------------- finalize: per-edge scalars -> outputs ----------------
__global__ void finalize(const float* __restrict__ P, const int* __restrict__ ei,
                         const float* __restrict__ pos, const int* __restrict__ batch,
                         const float* __restrict__ b2e, const float* __restrict__ b2f,
                         float* __restrict__ out) {
    __shared__ float ebin[NG];
    int t = threadIdx.x;
    if (t < NG) ebin[t] = 0.f;
    __syncthreads();
    int e = blockIdx.x * 256 + t;

    float se = b2e[0], sf = b2f[0];
#pragma unroll
    for (int nb = 0; nb < 8; ++nb)  se += P[(size_t)nb * E_CNT + e];
#pragma unroll
    for (int nb = 8; nb < 16; ++nb) sf += P[(size_t)nb * E_CNT + e];

    int s = ei[e], d = ei[E_CNT + e];
    float vx = pos[3 * s]     - pos[3 * d];
    float vy = pos[3 * s + 1] - pos[3 * d + 1];
    float vz = pos[3 * s + 2] - pos[3 * d + 2];
    float nrm = sqrtf(vx * vx + vy * vy + vz * vz);
    float inv = sf / fmaxf(nrm, 1e-12f);
    atomicAdd(&out[NG + 3 * s],     vx * inv);
    atomicAdd(&out[NG + 3 * s + 1], vy * inv);
    atomicAdd(&out[NG + 3 * s + 2], vz * inv);
    atomicAdd(&ebin[batch[s]], se);

    __syncthreads();
    if (t < NG) {
        float v = ebin[t];
        if (v != 0.f) atomicAdd(&out[t], v);
    }
}

extern "C" void kernel_launch(void* const* d_in, const int* in_sizes, int n_in,
                              void* d_out, int out_size, void* d_ws, size_t ws_size,
                              hipStream_t stream) {
    const float* x    = (const float*)d_in[0];
    const float* pos  = (const float*)d_in[1];
    const float* W1e  = (const float*)d_in[2];
    const float* b1e  = (const float*)d_in[3];
    const float* W2e  = (const float*)d_in[4];
    const float* b2e  = (const float*)d_in[5];
    const float* W1f  = (const float*)d_in[6];
    const float* b1f  = (const float*)d_in[7];
    const float* W2f  = (const float*)d_in[8];
    const float* b2f  = (const float*)d_in[9];
    const int*  batch = (const int*)d_in[10];
    const int*  ei    = (const int*)d_in[11];
    float* out        = (float*)d_out;

    if (ws_size < (size_t)WS_END) return;  // workspace too small — fail loudly

    char* ws = (char*)d_ws;
    uint32_t* xb32 = (uint32_t*)(ws + WS_XB);
    u16*      xb   = (u16*)(ws + WS_XB);
    u16*      wt   = (u16*)(ws + WS_WT);
    float*    b1c  = (float*)(ws + WS_B1);
    float*    w2c  = (float*)(ws + WS_W2);
    float*    P    = (float*)(ws + WS_P);

    hipMemsetAsync(d_out, 0, (size_t)out_size * sizeof(float), stream);

    cvt_x<<<78036, 256, 0, stream>>>(x, xb32);                       // 159,817,728 / 8 / 256
    prep_w<<<dim3(64, 48), 256, 0, stream>>>(W1e, W1f, wt);
    prep_small<<<8, 256, 0, stream>>>(b1e, b1f, W2e, W2f, b1c, w2c);
    gemm_mlp<<<dim3(16, 2048), 256, 0, stream>>>(xb, wt, b1c, w2c, ei, P);
    finalize<<<1024, 256, 0, stream>>>(P, ei, pos, batch, b2e, b2f, out);
}

// Round 4
// 2633.617 us; speedup vs baseline: 1.3618x; 1.3618x over previous
//
#include <hip/hip_runtime.h>
#include <cstdint>
#include <cstddef>

#define E_CNT   262144
#define NNODES  50000
#define EMB     512
#define KD      1536
#define ND      2048
#define NG      64
#define XROWS   (NNODES + E_CNT)

typedef unsigned short u16;
typedef short  s8v __attribute__((ext_vector_type(8)));
typedef float  f4v __attribute__((ext_vector_type(4)));

// ---- workspace layout (bytes) ----
#define WS_XB   0u                      // XROWS*512 bf16           = 319,635,456
#define WS_WT   319635456u              // 2048*1536 bf16           =   6,291,456
#define WS_B1   325926912u              // 2048 f32
#define WS_W2   325935104u              // 2048 f32
#define WS_P    325943296u              // 8*E f32                  =   8,388,608
#define WS_END  342720512u

__device__ __forceinline__ u16 f2bf(float f) {
    union { float f; uint32_t u; } v; v.f = f;
    uint32_t u = v.u;
    return (u16)((u + 0x7FFFu + ((u >> 16) & 1u)) >> 16);
}

// ---------------- x -> bf16 ----------------
__global__ void cvt_x(const float* __restrict__ x, uint32_t* __restrict__ xb) {
    size_t i = ((size_t)blockIdx.x * 256 + threadIdx.x) * 8;
    float4 a = *(const float4*)(x + i);
    float4 b = *(const float4*)(x + i + 4);
    uint4 r;
    r.x = (uint32_t)f2bf(a.x) | ((uint32_t)f2bf(a.y) << 16);
    r.y = (uint32_t)f2bf(a.z) | ((uint32_t)f2bf(a.w) << 16);
    r.z = (uint32_t)f2bf(b.x) | ((uint32_t)f2bf(b.y) << 16);
    r.w = (uint32_t)f2bf(b.z) | ((uint32_t)f2bf(b.w) << 16);
    *(uint4*)((char*)xb + i * 2) = r;
}

// ------- W1e|W1f -> WT[n][k] bf16 (tiled transpose) -------
__global__ void prep_w(const float* __restrict__ W1e, const float* __restrict__ W1f,
                       u16* __restrict__ wt) {
    __shared__ float tile[32][33];
    int n0 = blockIdx.x * 32, k0 = blockIdx.y * 32;
    int tx = threadIdx.x & 31, ty = threadIdx.x >> 5;   // 32 x 8
#pragma unroll
    for (int i = 0; i < 4; ++i) {
        int k = k0 + ty + i * 8, n = n0 + tx;
        float v = (n < 1024) ? W1e[k * 1024 + n] : W1f[k * 1024 + (n - 1024)];
        tile[ty + i * 8][tx] = v;
    }
    __syncthreads();
#pragma unroll
    for (int i = 0; i < 4; ++i) {
        int nl = ty + i * 8, kl = tx;
        wt[(size_t)(n0 + nl) * KD + k0 + kl] = f2bf(tile[kl][nl]);
    }
}

__global__ void prep_small(const float* __restrict__ b1e, const float* __restrict__ b1f,
                           const float* __restrict__ W2e, const float* __restrict__ W2f,
                           float* __restrict__ b1c, float* __restrict__ w2c) {
    int n = blockIdx.x * 256 + threadIdx.x;  // 0..2047
    if (n < 1024) { b1c[n] = b1e[n]; w2c[n] = W2e[n]; }
    else          { b1c[n] = b1f[n - 1024]; w2c[n] = W2f[n - 1024]; }
}

// ---------------- fused GEMM + gelu + W2-reduce ----------------
// grid = (8 n-tiles, 2048 m-tiles), 512 threads (8 waves, 2m x 4n wave grid).
// Tile 128x256, BK=64. 3-deep LDS pipeline, counted vmcnt (2-phase lookahead),
// XOR-swizzled tiles, XCD-grouped blocks. 1 block/CU, 2 waves/SIMD.
__global__ __launch_bounds__(512, 2)
void gemm_mlp(const u16* __restrict__ xb, const u16* __restrict__ wt,
              const float* __restrict__ b1c, const float* __restrict__ w2c,
              const int* __restrict__ ei, float* __restrict__ P) {
    __shared__ u16 Al[3][128 * 64];   // [buf][row][64] ; swizzled units
    __shared__ u16 Bl[3][256 * 64];
    __shared__ float part[128];

    // ---- XCD-grouping remap: o = bx + 8*by ; XCD = o % 8.
    // mb = (o&7) + 8*(o>>6), nb = (o>>3)&7  -> 8 nb-blocks of an mb on one XCD.
    const unsigned o = blockIdx.x + (blockIdx.y << 3);
    const int mb = (int)((o & 7u) + ((o >> 6) << 3));
    const int nb = (int)((o >> 3) & 7u);
    const int m0 = mb << 7;             // 128-row m tile
    const int n0 = nb << 8;             // 256-col n tile
    const int t  = threadIdx.x;
    const int l  = t & 63;
    const int w  = t >> 6;              // 0..7

    // staging: lane covers row-group lr (0..7), 16B unit `unit` (0..7)
    const int lr    = l >> 3;
    const int unit  = l & 7;
    const int sunit = (unit ^ lr) << 3;  // pre-swizzled source column (elems)

    int srcs[2], dsts[2];
#pragma unroll
    for (int i = 0; i < 2; ++i) {
        int e = m0 + i * 64 + w * 8 + lr;
        srcs[i] = ei[e];
        dsts[i] = ei[E_CNT + e];
    }

    if (t < 128) part[t] = 0.0f;

    const int wm = (w & 1) << 6;        // wave tile origin in m (0,64)
    const int wn = (w >> 1) << 6;       // wave tile origin in n (0,64,128,192)
    const int l15 = l & 15;

    float b1v[4], w2v[4];
#pragma unroll
    for (int nf = 0; nf < 4; ++nf) {
        int n = n0 + wn + nf * 16 + l15;
        b1v[nf] = b1c[n];
        w2v[nf] = w2c[n];
    }

    f4v acc[4][4];
#pragma unroll
    for (int mf = 0; mf < 4; ++mf)
#pragma unroll
        for (int nf = 0; nf < 4; ++nf)
            acc[mf][nf] = (f4v){0.f, 0.f, 0.f, 0.f};

    // ---- staging: 2 A-loads + 4 B-loads per thread per K-tile (vmcnt 6) ----
    auto stage = [&](u16* Ad, u16* Bd, int kt) {
        const int k0   = kt << 6;
        const int seg  = k0 >> 9;       // 0:src 1:dst 2:edge-token
        const int koff = k0 & 511;
#pragma unroll
        for (int i = 0; i < 2; ++i) {
            int row;
            if (seg == 0)      row = srcs[i];
            else if (seg == 1) row = dsts[i];
            else               row = NNODES + m0 + i * 64 + w * 8 + lr;
            const u16* g = xb + (size_t)row * EMB + koff + sunit;
            __builtin_amdgcn_global_load_lds(
                (const __attribute__((address_space(1))) void*)g,
                (__attribute__((address_space(3))) void*)(Ad + (i * 64 + w * 8) * 64),
                16, 0, 0);
        }
#pragma unroll
        for (int j = 0; j < 4; ++j) {
            int n = n0 + j * 64 + w * 8 + lr;
            const u16* g = wt + (size_t)n * KD + k0 + sunit;
            __builtin_amdgcn_global_load_lds(
                (const __attribute__((address_space(1))) void*)g,
                (__attribute__((address_space(3))) void*)(Bd + (j * 64 + w * 8) * 64),
                16, 0, 0);
        }
    };

    // read-side physical unit offsets (elems): logical unit = ks*4 + (l>>4);
    // fragment row&7 == l&7 for every mf/nf.
    const int po0 = (((l >> 4) ^ (l & 7)) << 3);
    const int po1 = (((4 | (l >> 4)) ^ (l & 7)) << 3);

    // ---- compute one K-tile: 16 ds_read_b128 then 32 MFMA ----
    auto compute = [&](const u16* Ab, const u16* Bb) {
        s8v a[2][4], b[2][4];
#pragma unroll
        for (int mf = 0; mf < 4; ++mf) {
            a[0][mf] = *(const s8v*)(Ab + (wm + mf * 16 + l15) * 64 + po0);
            a[1][mf] = *(const s8v*)(Ab + (wm + mf * 16 + l15) * 64 + po1);
        }
#pragma unroll
        for (int nf = 0; nf < 4; ++nf) {
            b[0][nf] = *(const s8v*)(Bb + (wn + nf * 16 + l15) * 64 + po0);
            b[1][nf] = *(const s8v*)(Bb + (wn + nf * 16 + l15) * 64 + po1);
        }
        __builtin_amdgcn_s_setprio(1);
#pragma unroll
        for (int ks = 0; ks < 2; ++ks)
#pragma unroll
            for (int mf = 0; mf < 4; ++mf)
#pragma unroll
                for (int nf = 0; nf < 4; ++nf)
                    acc[mf][nf] = __builtin_amdgcn_mfma_f32_16x16x32_bf16(
                        a[ks][mf], b[ks][nf], acc[mf][nf], 0, 0, 0);
        __builtin_amdgcn_s_setprio(0);
    };

    // rotating buffers
    u16 *Ac = Al[0], *An = Al[1], *As = Al[2];
    u16 *Bc = Bl[0], *Bn = Bl[1], *Bs = Bl[2];

    // prologue: tiles 0,1 staged and drained; tile 2 in flight
    stage(Ac, Bc, 0);
    stage(An, Bn, 1);
    __syncthreads();

    stage(As, Bs, 2);                      // vm: 6
    compute(Ac, Bc);                       // kt = 0
    { u16* tA = Ac; Ac = An; An = As; As = tA;
      u16* tB = Bc; Bc = Bn; Bn = Bs; Bs = tB; }

    for (int kt = 1; kt <= 21; ++kt) {
        asm volatile("s_waitcnt vmcnt(6)" ::: "memory");  // stage(kt) landed
        __builtin_amdgcn_s_barrier();                     // buf(kt) ready; staged buf free
        stage(As, Bs, kt + 2);                            // vm: 6 -> 12
        compute(Ac, Bc);
        { u16* tA = Ac; Ac = An; An = As; As = tA;
          u16* tB = Bc; Bc = Bn; Bn = Bs; Bs = tB; }
    }
    // kt = 22: stage(23) still in flight
    asm volatile("s_waitcnt vmcnt(6)" ::: "memory");
    __builtin_amdgcn_s_barrier();
    compute(Ac, Bc);
    { u16* tA = Ac; Ac = An; An = As; As = tA;
      u16* tB = Bc; Bc = Bn; Bn = Bs; Bs = tB; }
    // kt = 23: last tile
    asm volatile("s_waitcnt vmcnt(0)" ::: "memory");
    __builtin_amdgcn_s_barrier();
    compute(Ac, Bc);

    // ---- epilogue: bias + gelu(tanh) + *W2, reduce over this block's 256 cols ----
    // C layout: m = wm + mf*16 + (l>>4)*4 + r ; n = wn + nf*16 + (l&15)
#pragma unroll
    for (int mf = 0; mf < 4; ++mf) {
#pragma unroll
        for (int r = 0; r < 4; ++r) {
            float s = 0.f;
#pragma unroll
            for (int nf = 0; nf < 4; ++nf) {
                float h  = acc[mf][nf][r] + b1v[nf];
                float x2 = h * h;
                float pp = fmaf(x2, 0.044715f, 1.0f);
                float u2 = 1.5957691216f * h * pp;        // 2*sqrt(2/pi)*(h+0.044715h^3)
                float ex = __expf(-u2);
                float sg = __builtin_amdgcn_rcpf(1.0f + ex); // gelu = h*sigmoid(u2)
                s = fmaf(h * sg, w2v[nf], s);
            }
            s += __shfl_xor(s, 1);
            s += __shfl_xor(s, 2);
            s += __shfl_xor(s, 4);
            s += __shfl_xor(s, 8);
            if ((l & 15) == 0) {
                int m = wm + mf * 16 + ((l >> 4) << 2) + r;
                atomicAdd(&part[m], s);
            }
        }
    }
    __syncthreads();
    if (t < 128) P[(size_t)nb * E_CNT + m0 + t] = part[t];
}

// ---------------- finalize: per-edge scalars -> outputs ----------------
__global__ void finalize(const float* __restrict__ P, const int* __restrict__ ei,
                         const float* __restrict__ pos, const int* __restrict__ batch,
                         const float* __restrict__ b2e, const float* __restrict__ b2f,
                         float* __restrict__ out) {
    __shared__ float ebin[NG];
    int t = threadIdx.x;
    if (t < NG) ebin[t] = 0.f;
    __syncthreads();
    int e = blockIdx.x * 256 + t;

    float se = b2e[0], sf = b2f[0];
#pragma unroll
    for (int nb = 0; nb < 4; ++nb)  se += P[(size_t)nb * E_CNT + e];
#pragma unroll
    for (int nb = 4; nb < 8; ++nb)  sf += P[(size_t)nb * E_CNT + e];

    int s = ei[e], d = ei[E_CNT + e];
    float vx = pos[3 * s]     - pos[3 * d];
    float vy = pos[3 * s + 1] - pos[3 * d + 1];
    float vz = pos[3 * s + 2] - pos[3 * d + 2];
    float nrm = sqrtf(vx * vx + vy * vy + vz * vz);
    float inv = sf / fmaxf(nrm, 1e-12f);
    atomicAdd(&out[NG + 3 * s],     vx * inv);
    atomicAdd(&out[NG + 3 * s + 1], vy * inv);
    atomicAdd(&out[NG + 3 * s + 2], vz * inv);
    atomicAdd(&ebin[batch[s]], se);

    __syncthreads();
    if (t < NG) {
        float v = ebin[t];
        if (v != 0.f) atomicAdd(&out[t], v);
    }
}

extern "C" void kernel_launch(void* const* d_in, const int* in_sizes, int n_in,
                              void* d_out, int out_size, void* d_ws, size_t ws_size,
                              hipStream_t stream) {
    const float* x    = (const float*)d_in[0];
    const float* pos  = (const float*)d_in[1];
    const float* W1e  = (const float*)d_in[2];
    const float* b1e  = (const float*)d_in[3];
    const float* W2e  = (const float*)d_in[4];
    const float* b2e  = (const float*)d_in[5];
    const float* W1f  = (const float*)d_in[6];
    const float* b1f  = (const float*)d_in[7];
    const float* W2f  = (const float*)d_in[8];
    const float* b2f  = (const float*)d_in[9];
    const int*  batch = (const int*)d_in[10];
    const int*  ei    = (const int*)d_in[11];
    float* out        = (float*)d_out;

    if (ws_size < (size_t)WS_END) return;  // workspace too small — fail loudly

    char* ws = (char*)d_ws;
    uint32_t* xb32 = (uint32_t*)(ws + WS_XB);
    u16*      xb   = (u16*)(ws + WS_XB);
    u16*      wt   = (u16*)(ws + WS_WT);
    float*    b1c  = (float*)(ws + WS_B1);
    float*    w2c  = (float*)(ws + WS_W2);
    float*    P    = (float*)(ws + WS_P);

    hipMemsetAsync(d_out, 0, (size_t)out_size * sizeof(float), stream);

    cvt_x<<<78036, 256, 0, stream>>>(x, xb32);                       // 159,817,728 / 8 / 256
    prep_w<<<dim3(64, 48), 256, 0, stream>>>(W1e, W1f, wt);
    prep_small<<<8, 256, 0, stream>>>(b1e, b1f, W2e, W2f, b1c, w2c);
    gemm_mlp<<<dim3(8, 2048), 512, 0, stream>>>(xb, wt, b1c, w2c, ei, P);
    finalize<<<1024, 256, 0, stream>>>(P, ei, pos, batch, b2e, b2f, out);
}